// Round 17
// baseline (451.702 us; speedup 1.0000x reference)
//
#include <hip/hip_runtime.h>

// MemoryProjection: x_t = A x_{t-1} + in_t * Bd, out = all states (2048,8,64,64) fp32.
// Chunked: out[j*64+tau] = A^(tau+1) x0_j + sum_{k<=tau} (A^(tau-k) Bd) in[j*64+k]
// => one fp16 MFMA GEMM: C[m=(j,q)][nn=(tau,n)] = R16[m][:] . W16[nn][:], K=256
//    R16 = [in(64) | x0h(64) | x0h(64) | x0l(64)], W16 = [Kmat | Ph | Pl | Ph]
// kP (MERGED prep, 224 blocks x 1024 thr, TWO launches total):
//   0..63   chains: P[tau]=A^(tau+1) h/l MFMA -> W16 Ph/Pl (r15 code, dead stores cut)
//   64..191 transpose: inp -> R16[:,0:64) (r15 verbatim)
//   192..223 scan+Kmat: SELF-SUFFICIENT -- each block rebuilds Kv + A64 from A
//     (6 mms + 5 LDS-transposes squaring ladder + 8 serial matvecs + 7 Krylov
//      8-col steps), then 16 q-cols scan + 2 tau Kmat. No cross-block deps, so
//     chains/transpose/scan all overlap (r13's spin-wait disaster avoided).
//   Removes one launch boundary + kB's serialization behind kA (~32us prep -> ~20).
// kC: r15 verbatim (BK=32 dbuf, counted vmcnt, raw barriers, plain-store epilogue).

typedef _Float16 f16;
typedef __attribute__((ext_vector_type(8))) _Float16 f16x8;
typedef __attribute__((ext_vector_type(4))) float f32x4;

// ---------------- kP: chains | transpose | self-sufficient scan+Kmat ----------------
__global__ __launch_bounds__(1024) void kP_prep(
    const float* __restrict__ A, const float* __restrict__ Bm,
    const float* __restrict__ inp,
    f16* __restrict__ W16, f16* __restrict__ R16)
{
  __shared__ __align__(16) char sA[99328];
  int t = threadIdx.x;
  int blk = blockIdx.x;
  int wave = t >> 6, lane = t & 63;
  int tn = wave >> 2, tm = wave & 3;       // 4x4 grid of 16x16 tiles (16 waves)
  int kg = lane >> 4, fr = lane & 15;

  // shared mm: D = P * Q^T (row-major h/l), h/l compensated; trailing barrier.
  auto mm = [&](f16 (*Ph)[72], f16 (*Pl)[72], f16 (*Qh)[72], f16 (*Ql)[72],
                f16 (*Dh)[72], f16 (*Dl)[72]) {
    f32x4 acc = {};
    #pragma unroll
    for (int kk = 0; kk < 2; ++kk) {
      f16x8 ah = *(const f16x8*)&Ph[tn * 16 + fr][kk * 32 + kg * 8];
      f16x8 al = *(const f16x8*)&Pl[tn * 16 + fr][kk * 32 + kg * 8];
      f16x8 bh = *(const f16x8*)&Qh[tm * 16 + fr][kk * 32 + kg * 8];
      f16x8 bl = *(const f16x8*)&Ql[tm * 16 + fr][kk * 32 + kg * 8];
      acc = __builtin_amdgcn_mfma_f32_16x16x32_f16(ah, bh, acc, 0, 0, 0);
      acc = __builtin_amdgcn_mfma_f32_16x16x32_f16(ah, bl, acc, 0, 0, 0);
      acc = __builtin_amdgcn_mfma_f32_16x16x32_f16(al, bh, acc, 0, 0, 0);
    }
    #pragma unroll
    for (int r = 0; r < 4; ++r) {
      float v = acc[r];
      f16 h = (f16)v, l = (f16)(v - (float)h);
      Dh[tn * 16 + kg * 4 + r][tm * 16 + fr] = h;
      Dl[tn * 16 + kg * 4 + r][tm * 16 + fr] = l;
    }
    __syncthreads();
  };

  if (blk >= 64 && blk < 192) {
    // -------- transpose: one (j,qb) 64x128 tile --------
    float (*tile)[132] = (float (*)[132])sA;
    int bb = blk - 64;
    int j = bb >> 2, qb = (bb & 3) * 128;
    {
      int k = t >> 4, seg = (t & 15) * 8;
      const float* src = inp + j * 32768 + k * 512 + qb + seg;
      *(f32x4*)(&tile[k][seg])     = *(const f32x4*)(src);
      *(f32x4*)(&tile[k][seg + 4]) = *(const f32x4*)(src + 4);
    }
    __syncthreads();
    {
      int q = t & 127, ks8 = (t >> 7) * 8;
      f16 tmp[8];
      #pragma unroll
      for (int kk = 0; kk < 8; ++kk)
        tmp[kk] = (f16)tile[ks8 + kk][q];
      *(f16x8*)(R16 + ((size_t)(j * 512 + qb + q)) * 256 + ks8) =
          *(const f16x8*)tmp;
    }
    return;
  }

  if (blk >= 192) {
    // -------- self-sufficient scan + Kmat --------
    f16 (*Ah)[72]  = (f16 (*)[72])(sA + 0);
    f16 (*Al)[72]  = (f16 (*)[72])(sA + 9216);
    f16 (*C0h)[72] = (f16 (*)[72])(sA + 18432);
    f16 (*C0l)[72] = (f16 (*)[72])(sA + 27648);
    f16 (*C1h)[72] = (f16 (*)[72])(sA + 36864);
    f16 (*C1l)[72] = (f16 (*)[72])(sA + 46080);
    f16 (*Sh)[72]  = (f16 (*)[72])(sA + 55296);
    f16 (*Sl)[72]  = (f16 (*)[72])(sA + 64512);
    float* KvF  = (float*)(sA + 73728);   // [64][64] f32: KvF[j*64+n] = (A^j B)[n]
    float* xsvs = (float*)(sA + 90112);   // 16 waves x 144 f32

    auto T = [&](f16 (*Sxh)[72], f16 (*Sxl)[72], f16 (*Dxh)[72], f16 (*Dxl)[72]) {
      for (int idx = t; idx < 4096; idx += 1024) {
        int i2 = idx >> 6, j2 = idx & 63;
        Dxh[i2][j2] = Sxh[j2][i2];
        Dxl[i2][j2] = Sxl[j2][i2];
      }
      __syncthreads();
    };

    // init: A h/l row-major; C0 = Y1 = A^T h/l; KvF[0] = Bm
    for (int idx = t; idx < 4096; idx += 1024) {
      float v = A[idx];
      int r = idx >> 6, c2 = idx & 63;
      f16 h = (f16)v, l = (f16)(v - (float)h);
      Ah[r][c2] = h;  Al[r][c2] = l;
      C0h[c2][r] = h; C0l[c2][r] = l;
    }
    if (t < 64) KvF[t] = Bm[t];
    __syncthreads();

    // Krylov first 8 cols: KvF[j] = A * KvF[j-1]
    for (int j = 1; j < 8; ++j) {
      float acc = 0.f;
      if (t < 64) {
        #pragma unroll 8
        for (int m = 0; m < 64; ++m)
          acc += ((float)Ah[t][m] + (float)Al[t][m]) * KvF[(j - 1) * 64 + m];
      }
      __syncthreads();
      if (t < 64) KvF[j * 64 + t] = acc;
      __syncthreads();
    }

    // squaring ladder (Y = transposed powers, H = row-major powers)
    mm(C0h, C0l, Ah, Al, C1h, C1l);      // Y2
    T(C1h, C1l, C0h, C0l);               // H2
    mm(C1h, C1l, C0h, C0l, Sh, Sl);      // Y4 = Y2*H2^T
    T(Sh, Sl, C1h, C1l);                 // H4
    mm(Sh, Sl, C1h, C1l, C0h, C0l);      // Y8 = Y4*H4^T  (C0 = (A^8)^T)

    // Krylov 8-col blocks: KvF[8k+i] = A8 * KvF[8(k-1)+i]; A8[n][m] = Y8[m][n]
    for (int k = 1; k < 8; ++k) {
      float acc = 0.f;
      int n = t >> 3, i = t & 7;
      if (t < 512) {
        #pragma unroll 8
        for (int m = 0; m < 64; ++m)
          acc += ((float)C0h[m][n] + (float)C0l[m][n]) * KvF[(8 * (k - 1) + i) * 64 + m];
      }
      __syncthreads();
      if (t < 512) KvF[(8 * k + i) * 64 + n] = acc;
      __syncthreads();
    }

    // Kmat: 2 tau per block (KvF complete)
    {
      int tau = (blk - 192) * 2 + (t >> 9);
      int sub = t & 511;
      int wn = sub & 63, k8 = sub >> 6;
      f16* wrow = W16 + ((size_t)(tau * 64 + wn)) * 256 + k8 * 8;
      #pragma unroll
      for (int ki = 0; ki < 8; ++ki) {
        int k = k8 * 8 + ki;
        wrow[ki] = (f16)((k <= tau) ? KvF[(tau - k) * 64 + wn] : 0.0f);
      }
    }

    // ladder continues: A64 (row-major h/l) into S
    T(C0h, C0l, C1h, C1l);               // H8
    mm(C1h, C1l, C0h, C0l, Sh, Sl);      // H16 = H8*Y8^T = A16
    T(Sh, Sl, C0h, C0l);                 // Y16
    mm(Sh, Sl, C0h, C0l, C1h, C1l);      // H32 = H16*Y16^T = A32
    T(C1h, C1l, C0h, C0l);               // Y32
    mm(C1h, C1l, C0h, C0l, Sh, Sl);      // H64 = A64

    // scan: 16 waves, one q each; ar in regs, kvr from KvF (LDS)
    int wv = t >> 6, L = t & 63;
    int q = (blk - 192) * 16 + wv;
    float* xs = xsvs + wv * 144;
    float* vs = xs + 72;
    float ar[64];
    #pragma unroll 8
    for (int m = 0; m < 64; ++m)
      ar[m] = (float)Sh[L][m] + (float)Sl[L][m];
    float x = 0.f;
    float v = inp[(size_t)L * 512 + q];
    for (int j = 0; j < 32; ++j) {
      float vn = (j < 31) ? inp[(size_t)((j + 1) * 64 + L) * 512 + q] : 0.f;
      f16 hh = (f16)x, ll = (f16)(x - (float)hh);
      f16* row = R16 + ((size_t)(j * 512 + q)) * 256;
      row[64 + L] = hh; row[128 + L] = hh; row[192 + L] = ll;
      xs[L] = x;
      vs[L] = v;
      float a0 = 0.f, a1 = 0.f, c0 = 0.f, c1 = 0.f;
      #pragma unroll
      for (int m = 0; m < 64; m += 4) {
        f32x4 xv = *(const f32x4*)(xs + m);   // same-addr broadcast
        f32x4 vv = *(const f32x4*)(vs + m);
        a0 += ar[m] * xv.x + ar[m + 1] * xv.y;
        a1 += ar[m + 2] * xv.z + ar[m + 3] * xv.w;
        c0 += KvF[(63 - m) * 64 + L] * vv.x + KvF[(62 - m) * 64 + L] * vv.y;
        c1 += KvF[(61 - m) * 64 + L] * vv.z + KvF[(60 - m) * 64 + L] * vv.w;
      }
      x = (a0 + a1) + (c0 + c1);
      v = vn;
    }
    return;
  }

  // -------- chain blocks 0..63 (r15 kA, dead Kv/A64 stores removed) --------
  f16 (*Ah)[72]  = (f16 (*)[72])(sA + 0 * 9216);
  f16 (*Al)[72]  = (f16 (*)[72])(sA + 1 * 9216);
  f16 (*B0h)[72] = (f16 (*)[72])(sA + 2 * 9216);
  f16 (*B0l)[72] = (f16 (*)[72])(sA + 3 * 9216);
  f16 (*B1h)[72] = (f16 (*)[72])(sA + 4 * 9216);
  f16 (*B1l)[72] = (f16 (*)[72])(sA + 5 * 9216);
  f16 (*Y8h)[72] = (f16 (*)[72])(sA + 6 * 9216);
  f16 (*Y8l)[72] = (f16 (*)[72])(sA + 7 * 9216);
  f16 (*Ybh)[72] = (f16 (*)[72])(sA + 8 * 9216);
  f16 (*Ybl)[72] = (f16 (*)[72])(sA + 9 * 9216);

  int tau = blk;
  int e = tau + 1;
  int a = e >> 3, b = e & 7;

  auto cpy2 = [&](f16 (*Sxh)[72], f16 (*Sxl)[72], f16 (*Dxh)[72], f16 (*Dxl)[72]) {
    const unsigned* sh = (const unsigned*)Sxh; unsigned* dh = (unsigned*)Dxh;
    const unsigned* sl = (const unsigned*)Sxl; unsigned* dl = (unsigned*)Dxl;
    for (int idx = t; idx < 2304; idx += 1024) { dh[idx] = sh[idx]; dl[idx] = sl[idx]; }
  };

  for (int idx = t; idx < 4096; idx += 1024) {
    float v = A[idx];
    int r = idx >> 6, c2 = idx & 63;
    f16 h = (f16)v, l = (f16)(v - (float)h);
    Ah[r][c2] = h;  Al[r][c2] = l;
    B0h[c2][r] = h; B0l[c2][r] = l;
  }
  __syncthreads();

  f16 (*curH)[72] = B0h; f16 (*curL)[72] = B0l;
  f16 (*othH)[72] = B1h; f16 (*othL)[72] = B1l;
  auto swp = [&]() {
    f16 (*tH)[72] = curH; curH = othH; othH = tH;
    f16 (*tL)[72] = curL; curL = othL; othL = tL;
  };

  if (b == 1) cpy2(curH, curL, Ybh, Ybl);

  int loMax = (a >= 1) ? 8 : b;
  for (int i = 2; i <= loMax; ++i) {
    mm(curH, curL, Ah, Al, othH, othL);
    swp();
    if (i == b) cpy2(curH, curL, Ybh, Ybl);
    if (i == 8) cpy2(curH, curL, Y8h, Y8l);
  }

  f16 (*Rh)[72]; f16 (*Rl)[72]; bool tr;
  if (a == 0) {
    Rh = curH; Rl = curL; tr = true;                // result = Y_b^T
  } else {
    for (int idx = t; idx < 4096; idx += 1024) {
      int i = idx >> 6, j = idx & 63;
      othH[i][j] = curH[j][i];
      othL[i][j] = curL[j][i];
    }
    swp();
    __syncthreads();
    for (int a2 = 2; a2 <= a; ++a2) {               // H_{a+1} = mfma(H_a, Y8)
      mm(curH, curL, Y8h, Y8l, othH, othL);
      swp();
    }
    if (b >= 1) {                                   // P = mfma(H_a, Y_b)
      mm(curH, curL, Ybh, Ybl, othH, othL);
      swp();
    }
    Rh = curH; Rl = curL; tr = false;
  }

  for (int idx = t; idx < 4096; idx += 1024) {
    int wn = idx >> 6, m = idx & 63;
    f16 h = tr ? Rh[m][wn] : Rh[wn][m];
    f16 l = tr ? Rl[m][wn] : Rl[wn][m];
    f16* wrow = W16 + ((size_t)(tau * 64 + wn)) * 256;
    wrow[64 + m] = h; wrow[128 + m] = l; wrow[192 + m] = h;
  }
}

// ---------------- kC: C[16384 x 4096] = R16 @ W16^T (r15 verbatim) ----------------
#define STAGE32(ks, dbuf)                                                       \
  { _Pragma("unroll")                                                           \
    for (int it = 0; it < 2; ++it) {                                            \
      __builtin_amdgcn_global_load_lds(                                         \
        (const __attribute__((address_space(1))) void*)                         \
          (R16 + ((size_t)(mtb + w32 + it * 16 + l4)) * 256 + (ks) * 32 + swc32),\
        (__attribute__((address_space(3))) void*)((dbuf) + w * 1024 + it * 512),\
        16, 0, 0);                                                              \
      __builtin_amdgcn_global_load_lds(                                         \
        (const __attribute__((address_space(1))) void*)                         \
          (W16 + ((size_t)(ntb + w32 + it * 16 + l4)) * 256 + (ks) * 32 + swc32),\
        (__attribute__((address_space(3))) void*)((dbuf) + 4096 + w * 1024 + it * 512),\
        16, 0, 0);                                                              \
    } }

#define KSTEP32(sbuf)                                                           \
  { f16x8 af[4], bf[4];                                                         \
    _Pragma("unroll")                                                           \
    for (int i = 0; i < 4; ++i) {                                               \
      af[i] = *(const f16x8*)((sbuf) + (wr * 64 + i * 16 + fr) * 32 + scol);    \
      bf[i] = *(const f16x8*)((sbuf) + 4096 + (wc * 64 + i * 16 + fr) * 32 + scol);\
    }                                                                           \
    _Pragma("unroll")                                                           \
    for (int mi = 0; mi < 4; ++mi)                                              \
      _Pragma("unroll")                                                         \
      for (int ni = 0; ni < 4; ++ni)                                            \
        acc[mi][ni] = __builtin_amdgcn_mfma_f32_16x16x32_f16(                   \
            af[mi], bf[ni], acc[mi][ni], 0, 0, 0);                              \
  }

#define WAITN(n) asm volatile("s_waitcnt vmcnt(" #n ")" ::: "memory")
#define BAR()                                                                   \
  { __builtin_amdgcn_sched_barrier(0); __builtin_amdgcn_s_barrier();            \
    __builtin_amdgcn_sched_barrier(0); }

__global__ __launch_bounds__(256, 4) void kC_gemm(
    const f16* __restrict__ R16, const f16* __restrict__ W16,
    float* __restrict__ out)
{
  __shared__ __align__(16) char smem[34816];     // 2x16KB staging; epilogue alias
  f16* b0v = (f16*)smem;
  f16* b1v = b0v + 8192;
  float (*stg)[68] = (float (*)[68])smem;        // 34816B, aliased

  int wg = blockIdx.x;
  int swz = (wg & 7) * 512 + (wg >> 3);          // XCD-contiguous mt ranges
  int mt = swz >> 5, nt = swz & 31;
  int t = threadIdx.x, w = t >> 6, lane = t & 63;
  int wr = w >> 1, wc = w & 1;
  int kg = lane >> 4, fr = lane & 15;

  int l4 = lane >> 2;
  int swc32 = 8 * ((lane & 3) ^ ((lane >> 3) & 3));   // pre-swizzled src col (f16)
  int w32 = w * 32;
  int mtb = mt * 128, ntb = nt * 128;
  int scol = 8 * (kg ^ ((fr >> 1) & 3));              // swizzle-matched read col

  f32x4 acc[4][4] = {};

  STAGE32(0, b0v);
  STAGE32(1, b1v); WAITN(4); BAR(); KSTEP32(b0v); BAR();
  STAGE32(2, b0v); WAITN(4); BAR(); KSTEP32(b1v); BAR();
  STAGE32(3, b1v); WAITN(4); BAR(); KSTEP32(b0v); BAR();
  STAGE32(4, b0v); WAITN(4); BAR(); KSTEP32(b1v); BAR();
  STAGE32(5, b1v); WAITN(4); BAR(); KSTEP32(b0v); BAR();
  STAGE32(6, b0v); WAITN(4); BAR(); KSTEP32(b1v); BAR();
  STAGE32(7, b1v); WAITN(4); BAR(); KSTEP32(b0v); BAR();
  WAITN(0); BAR(); KSTEP32(b1v); BAR();

  int j = mt >> 2, q0 = (mt & 3) * 128;
  #pragma unroll
  for (int half = 0; half < 2; ++half) {
    if (wc == half) {
      #pragma unroll
      for (int mi = 0; mi < 4; ++mi)
        #pragma unroll
        for (int ni = 0; ni < 4; ++ni)
          #pragma unroll
          for (int r = 0; r < 4; ++r)
            stg[wr * 64 + mi * 16 + kg * 4 + r][ni * 16 + fr] = acc[mi][ni][r];
    }
    asm volatile("s_waitcnt lgkmcnt(0)" ::: "memory");
    BAR();
    int tau_g = nt * 2 + half;
    float* obase = out + (size_t)j * 2097152 + (size_t)tau_g * 32768 + (size_t)q0 * 64;
    #pragma unroll
    for (int it = 0; it < 8; ++it) {
      int fi = it * 1024 + t * 4;
      int rr = fi >> 6, cc = fi & 63;
      *(f32x4*)(obase + fi) = *(const f32x4*)(&stg[rr][cc]);
    }
    BAR();
  }
}

extern "C" void kernel_launch(void* const* d_in, const int* in_sizes, int n_in,
                              void* d_out, int out_size, void* d_ws, size_t ws_size,
                              hipStream_t stream)
{
  (void)in_sizes; (void)n_in; (void)out_size; (void)ws_size;
  const float* inp = (const float*)d_in[0];   // (2048, 8, 64) fp32
  const float* A   = (const float*)d_in[1];   // (64, 64) fp32
  const float* Bm  = (const float*)d_in[2];   // (64, 1) fp32
  float* out = (float*)d_out;                 // (2048, 8, 64, 64) fp32

  float* ws = (float*)d_ws;
  f16*  W16  = (f16*)(ws + 8192);             // 4096*256 f16 (2 MB)
  f16*  R16  = (f16*)((char*)d_ws + 2129920); // 16384*256 f16 (8 MB)

  hipLaunchKernelGGL(kP_prep, dim3(224),  dim3(1024), 0, stream, A, Bm, inp, W16, R16);
  hipLaunchKernelGGL(kC_gemm, dim3(4096), dim3(256),  0, stream, R16, W16, out);
}

// Round 18
// 100.702 us; speedup vs baseline: 4.4855x; 4.4855x over previous
//
#include <hip/hip_runtime.h>

// MemoryProjection: x_t = A x_{t-1} + in_t * Bd, out = all states (2048,8,64,64) fp32.
// Chunked: out[j*64+tau] = A^(tau+1) x0_j + sum_{k<=tau} (A^(tau-k) Bd) in[j*64+k]
// => one fp16 MFMA GEMM: C[m=(j,q)][nn=(tau,n)] = R16[m][:] . W16[nn][:], K=256
//    R16 = [in(64) | x0h(64) | x0h(64) | x0l(64)], W16 = [Kmat | Ph | Pl | Ph]
// r17 finding: kC ~= 42us (write floor); prep ~= 55us is the remaining slack.
// THIS ROUND (r15 base + 2 surgical write-coalescing fixes in prep):
//  - transpose R16 write: was 64 lanes x 16B at 512B stride (64 lines/store);
//    now 8 lanes/row x 16B contiguous (8 lines/store). LDS tile pad 132->133
//    (column-ish reads become 2-lane/bank = free).
//  - Kmat W16 write: was scalar 2B at 512B lane stride; now 4 lanes/row x 32B
//    contiguous (LDS reads become same-addr broadcast).
// kA: blocks 0..63 chains (h/l MFMA, 1024thr ok: no big per-thread arrays);
//     64..191 transpose. kB(256thr): 0..63 Kmat; 64..191 conv+scan (needs 256-thr
//     block for ar[64]+kvr[64] in regs -- r17 spill lesson). kC: r15 verbatim.

typedef _Float16 f16;
typedef __attribute__((ext_vector_type(8))) _Float16 f16x8;
typedef __attribute__((ext_vector_type(4))) float f32x4;

// ---------------- kA: powers via h/l MFMA (+ transpose blocks) ----------------
__global__ __launch_bounds__(1024) void kA_pow(
    const float* __restrict__ A, const float* __restrict__ Bm,
    const float* __restrict__ inp,
    float* __restrict__ A64, float* __restrict__ Kv,
    f16* __restrict__ W16, f16* __restrict__ R16)
{
  __shared__ __align__(16) char sA[92160];   // 10 x 9216B, carved below
  int t = threadIdx.x;

  if (blockIdx.x >= 64) {
    // -------- transpose: one (j,qb) 64x128 tile, 1024 threads --------
    float (*tile)[133] = (float (*)[133])sA;       // 34048B, aliases chain bufs
    int bb = blockIdx.x - 64;
    int j = bb >> 2, qb = (bb & 3) * 128;
    {
      int k = t >> 4, seg = (t & 15) * 8;
      const float* src = inp + j * 32768 + k * 512 + qb + seg;
      *(f32x4*)(&tile[k][seg])     = *(const f32x4*)(src);
      *(f32x4*)(&tile[k][seg + 4]) = *(const f32x4*)(src + 4);
    }
    __syncthreads();
    {
      // write-coalesced: 8 lanes cover one row's 128B in-part
      int qr = t >> 3, col8 = (t & 7) * 8;
      f16 tmp[8];
      #pragma unroll
      for (int kk = 0; kk < 8; ++kk)
        tmp[kk] = (f16)tile[col8 + kk][qr];
      *(f16x8*)(R16 + ((size_t)(j * 512 + qb + qr)) * 256 + col8) =
          *(const f16x8*)tmp;
    }
    return;
  }

  f16 (*Ah)[72]  = (f16 (*)[72])(sA + 0 * 9216);
  f16 (*Al)[72]  = (f16 (*)[72])(sA + 1 * 9216);
  f16 (*B0h)[72] = (f16 (*)[72])(sA + 2 * 9216);
  f16 (*B0l)[72] = (f16 (*)[72])(sA + 3 * 9216);
  f16 (*B1h)[72] = (f16 (*)[72])(sA + 4 * 9216);
  f16 (*B1l)[72] = (f16 (*)[72])(sA + 5 * 9216);
  f16 (*Y8h)[72] = (f16 (*)[72])(sA + 6 * 9216);
  f16 (*Y8l)[72] = (f16 (*)[72])(sA + 7 * 9216);
  f16 (*Ybh)[72] = (f16 (*)[72])(sA + 8 * 9216);
  f16 (*Ybl)[72] = (f16 (*)[72])(sA + 9 * 9216);

  int tau = blockIdx.x;
  int e = tau + 1;
  int a = e >> 3, b = e & 7;
  int wave = t >> 6, lane = t & 63;
  int tn = wave >> 2, tm = wave & 3;       // 4x4 grid of 16x16 tiles
  int kg = lane >> 4, fr = lane & 15;

  auto mm = [&](f16 (*Ph)[72], f16 (*Pl)[72], f16 (*Qh)[72], f16 (*Ql)[72],
                f16 (*Dh)[72], f16 (*Dl)[72]) {
    f32x4 acc = {};
    #pragma unroll
    for (int kk = 0; kk < 2; ++kk) {
      f16x8 ah = *(const f16x8*)&Ph[tn * 16 + fr][kk * 32 + kg * 8];
      f16x8 al = *(const f16x8*)&Pl[tn * 16 + fr][kk * 32 + kg * 8];
      f16x8 bh = *(const f16x8*)&Qh[tm * 16 + fr][kk * 32 + kg * 8];
      f16x8 bl = *(const f16x8*)&Ql[tm * 16 + fr][kk * 32 + kg * 8];
      acc = __builtin_amdgcn_mfma_f32_16x16x32_f16(ah, bh, acc, 0, 0, 0);
      acc = __builtin_amdgcn_mfma_f32_16x16x32_f16(ah, bl, acc, 0, 0, 0);
      acc = __builtin_amdgcn_mfma_f32_16x16x32_f16(al, bh, acc, 0, 0, 0);
    }
    #pragma unroll
    for (int r = 0; r < 4; ++r) {
      float v = acc[r];
      f16 h = (f16)v, l = (f16)(v - (float)h);
      Dh[tn * 16 + kg * 4 + r][tm * 16 + fr] = h;
      Dl[tn * 16 + kg * 4 + r][tm * 16 + fr] = l;
    }
    __syncthreads();
  };
  auto cpy2 = [&](f16 (*Sh)[72], f16 (*Sl)[72], f16 (*Dh)[72], f16 (*Dl)[72]) {
    const unsigned* sh = (const unsigned*)Sh; unsigned* dh = (unsigned*)Dh;
    const unsigned* sl = (const unsigned*)Sl; unsigned* dl = (unsigned*)Dl;
    for (int idx = t; idx < 2304; idx += 1024) { dh[idx] = sh[idx]; dl[idx] = sl[idx]; }
  };

  for (int idx = t; idx < 4096; idx += 1024) {
    float v = A[idx];
    int r = idx >> 6, c2 = idx & 63;
    f16 h = (f16)v, l = (f16)(v - (float)h);
    Ah[r][c2] = h;  Al[r][c2] = l;
    B0h[c2][r] = h; B0l[c2][r] = l;
  }
  __syncthreads();

  f16 (*curH)[72] = B0h; f16 (*curL)[72] = B0l;
  f16 (*othH)[72] = B1h; f16 (*othL)[72] = B1l;
  auto swp = [&]() {
    f16 (*tH)[72] = curH; curH = othH; othH = tH;
    f16 (*tL)[72] = curL; curL = othL; othL = tL;
  };

  if (b == 1) cpy2(curH, curL, Ybh, Ybl);

  int loMax = (a >= 1) ? 8 : b;
  for (int i = 2; i <= loMax; ++i) {
    mm(curH, curL, Ah, Al, othH, othL);
    swp();
    if (i == b) cpy2(curH, curL, Ybh, Ybl);
    if (i == 8) cpy2(curH, curL, Y8h, Y8l);
  }

  f16 (*Rh)[72]; f16 (*Rl)[72]; bool tr;
  if (a == 0) {
    Rh = curH; Rl = curL; tr = true;                // result = Y_b^T
  } else {
    for (int idx = t; idx < 4096; idx += 1024) {
      int i = idx >> 6, j = idx & 63;
      othH[i][j] = curH[j][i];
      othL[i][j] = curL[j][i];
    }
    swp();
    __syncthreads();
    for (int a2 = 2; a2 <= a; ++a2) {               // H_{a+1} = mfma(H_a, Y8)
      mm(curH, curL, Y8h, Y8l, othH, othL);
      swp();
    }
    if (b >= 1) {                                   // P = mfma(H_a, Y_b)
      mm(curH, curL, Ybh, Ybl, othH, othL);
      swp();
    }
    Rh = curH; Rl = curL; tr = false;
  }

  for (int idx = t; idx < 4096; idx += 1024) {
    int wn = idx >> 6, m = idx & 63;
    f16 h = tr ? Rh[m][wn] : Rh[wn][m];
    f16 l = tr ? Rl[m][wn] : Rl[wn][m];
    f16* wrow = W16 + ((size_t)(tau * 64 + wn)) * 256;
    wrow[64 + m] = h; wrow[128 + m] = l; wrow[192 + m] = h;
    if (tau == 63) A64[idx] = (float)h + (float)l;
  }
  if (t < 64) {
    float s = 0.f;
    #pragma unroll 8
    for (int m = 0; m < 64; ++m) {
      float pv = tr ? ((float)Rh[m][t] + (float)Rl[m][t])
                    : ((float)Rh[t][m] + (float)Rl[t][m]);
      s += pv * Bm[m];
    }
    if (tau < 63) Kv[(tau + 1) * 64 + t] = s;
    else          Kv[t] = Bm[t];
  }
}

// ---------------- kB: Kmat rows (write-coalesced) | fused conv+scan ----------------
__global__ __launch_bounds__(256) void kB_prep(
    const float* __restrict__ inp, const float* __restrict__ Kv,
    const float* __restrict__ A64,
    f16* __restrict__ R16, f16* __restrict__ W16)
{
  __shared__ __align__(16) float sm[64 * 66];
  int t = threadIdx.x;
  int b = blockIdx.x;
  if (b < 64) {
    int tau = b;
    for (int idx = t; idx < 4096; idx += 256) sm[idx] = Kv[idx];
    __syncthreads();
    // write-coalesced: 4 lanes per W16 row, each writes 16 contiguous f16 (32B)
    int wn = t >> 2, c4 = (t & 3) * 16;
    f16 tmp[16];
    #pragma unroll
    for (int ki = 0; ki < 16; ++ki) {
      int k = c4 + ki;
      tmp[ki] = (f16)((k <= tau) ? sm[(tau - k) * 64 + wn] : 0.0f);
    }
    f16* wrow = W16 + ((size_t)(tau * 64 + wn)) * 256 + c4;
    *(f16x8*)(wrow)     = *(const f16x8*)(tmp);
    *(f16x8*)(wrow + 8) = *(const f16x8*)(tmp + 8);
  } else {
    int wv = t >> 6, L = t & 63;
    int q = (b - 64) * 4 + wv;
    float* xs = sm + wv * 144;
    float* vs = xs + 72;
    float ar[64], kvr[64];
    #pragma unroll
    for (int m = 0; m < 64; m += 4) {
      f32x4 v4 = *(const f32x4*)(A64 + L * 64 + m);
      ar[m] = v4.x; ar[m + 1] = v4.y; ar[m + 2] = v4.z; ar[m + 3] = v4.w;
    }
    #pragma unroll
    for (int k = 0; k < 64; ++k) kvr[k] = Kv[(63 - k) * 64 + L];
    float x = 0.f;
    float v = inp[(size_t)L * 512 + q];
    for (int j = 0; j < 32; ++j) {
      float vn = (j < 31) ? inp[(size_t)((j + 1) * 64 + L) * 512 + q] : 0.f;
      f16 hh = (f16)x, ll = (f16)(x - (float)hh);
      f16* row = R16 + ((size_t)(j * 512 + q)) * 256;
      row[64 + L] = hh; row[128 + L] = hh; row[192 + L] = ll;
      xs[L] = x;
      vs[L] = v;
      float a0 = 0.f, a1 = 0.f, c0 = 0.f, c1 = 0.f;
      #pragma unroll
      for (int m = 0; m < 64; m += 4) {
        f32x4 xv = *(const f32x4*)(xs + m);   // same-addr broadcast, conflict-free
        f32x4 vv = *(const f32x4*)(vs + m);
        a0 += ar[m] * xv.x + ar[m + 1] * xv.y;
        a1 += ar[m + 2] * xv.z + ar[m + 3] * xv.w;
        c0 += kvr[m] * vv.x + kvr[m + 1] * vv.y;
        c1 += kvr[m + 2] * vv.z + kvr[m + 3] * vv.w;
      }
      x = (a0 + a1) + (c0 + c1);
      v = vn;
    }
  }
}

// ---------------- kC: C[16384 x 4096] = R16 @ W16^T (r15 verbatim) ----------------
#define STAGE32(ks, dbuf)                                                       \
  { _Pragma("unroll")                                                           \
    for (int it = 0; it < 2; ++it) {                                            \
      __builtin_amdgcn_global_load_lds(                                         \
        (const __attribute__((address_space(1))) void*)                         \
          (R16 + ((size_t)(mtb + w32 + it * 16 + l4)) * 256 + (ks) * 32 + swc32),\
        (__attribute__((address_space(3))) void*)((dbuf) + w * 1024 + it * 512),\
        16, 0, 0);                                                              \
      __builtin_amdgcn_global_load_lds(                                         \
        (const __attribute__((address_space(1))) void*)                         \
          (W16 + ((size_t)(ntb + w32 + it * 16 + l4)) * 256 + (ks) * 32 + swc32),\
        (__attribute__((address_space(3))) void*)((dbuf) + 4096 + w * 1024 + it * 512),\
        16, 0, 0);                                                              \
    } }

#define KSTEP32(sbuf)                                                           \
  { f16x8 af[4], bf[4];                                                         \
    _Pragma("unroll")                                                           \
    for (int i = 0; i < 4; ++i) {                                               \
      af[i] = *(const f16x8*)((sbuf) + (wr * 64 + i * 16 + fr) * 32 + scol);    \
      bf[i] = *(const f16x8*)((sbuf) + 4096 + (wc * 64 + i * 16 + fr) * 32 + scol);\
    }                                                                           \
    _Pragma("unroll")                                                           \
    for (int mi = 0; mi < 4; ++mi)                                              \
      _Pragma("unroll")                                                         \
      for (int ni = 0; ni < 4; ++ni)                                            \
        acc[mi][ni] = __builtin_amdgcn_mfma_f32_16x16x32_f16(                   \
            af[mi], bf[ni], acc[mi][ni], 0, 0, 0);                              \
  }

#define WAITN(n) asm volatile("s_waitcnt vmcnt(" #n ")" ::: "memory")
#define BAR()                                                                   \
  { __builtin_amdgcn_sched_barrier(0); __builtin_amdgcn_s_barrier();            \
    __builtin_amdgcn_sched_barrier(0); }

__global__ __launch_bounds__(256, 4) void kC_gemm(
    const f16* __restrict__ R16, const f16* __restrict__ W16,
    float* __restrict__ out)
{
  __shared__ __align__(16) char smem[34816];     // 2x16KB staging; epilogue alias
  f16* b0v = (f16*)smem;
  f16* b1v = b0v + 8192;
  float (*stg)[68] = (float (*)[68])smem;        // 34816B, aliased

  int wg = blockIdx.x;
  int swz = (wg & 7) * 512 + (wg >> 3);          // XCD-contiguous mt ranges
  int mt = swz >> 5, nt = swz & 31;
  int t = threadIdx.x, w = t >> 6, lane = t & 63;
  int wr = w >> 1, wc = w & 1;
  int kg = lane >> 4, fr = lane & 15;

  int l4 = lane >> 2;
  int swc32 = 8 * ((lane & 3) ^ ((lane >> 3) & 3));   // pre-swizzled src col (f16)
  int w32 = w * 32;
  int mtb = mt * 128, ntb = nt * 128;
  int scol = 8 * (kg ^ ((fr >> 1) & 3));              // swizzle-matched read col

  f32x4 acc[4][4] = {};

  STAGE32(0, b0v);
  STAGE32(1, b1v); WAITN(4); BAR(); KSTEP32(b0v); BAR();
  STAGE32(2, b0v); WAITN(4); BAR(); KSTEP32(b1v); BAR();
  STAGE32(3, b1v); WAITN(4); BAR(); KSTEP32(b0v); BAR();
  STAGE32(4, b0v); WAITN(4); BAR(); KSTEP32(b1v); BAR();
  STAGE32(5, b1v); WAITN(4); BAR(); KSTEP32(b0v); BAR();
  STAGE32(6, b0v); WAITN(4); BAR(); KSTEP32(b1v); BAR();
  STAGE32(7, b1v); WAITN(4); BAR(); KSTEP32(b0v); BAR();
  WAITN(0); BAR(); KSTEP32(b1v); BAR();

  int j = mt >> 2, q0 = (mt & 3) * 128;
  #pragma unroll
  for (int half = 0; half < 2; ++half) {
    if (wc == half) {
      #pragma unroll
      for (int mi = 0; mi < 4; ++mi)
        #pragma unroll
        for (int ni = 0; ni < 4; ++ni)
          #pragma unroll
          for (int r = 0; r < 4; ++r)
            stg[wr * 64 + mi * 16 + kg * 4 + r][ni * 16 + fr] = acc[mi][ni][r];
    }
    asm volatile("s_waitcnt lgkmcnt(0)" ::: "memory");
    BAR();
    int tau_g = nt * 2 + half;
    float* obase = out + (size_t)j * 2097152 + (size_t)tau_g * 32768 + (size_t)q0 * 64;
    #pragma unroll
    for (int it = 0; it < 8; ++it) {
      int fi = it * 1024 + t * 4;
      int rr = fi >> 6, cc = fi & 63;
      *(f32x4*)(obase + fi) = *(const f32x4*)(&stg[rr][cc]);
    }
    BAR();
  }
}

extern "C" void kernel_launch(void* const* d_in, const int* in_sizes, int n_in,
                              void* d_out, int out_size, void* d_ws, size_t ws_size,
                              hipStream_t stream)
{
  (void)in_sizes; (void)n_in; (void)out_size; (void)ws_size;
  const float* inp = (const float*)d_in[0];   // (2048, 8, 64) fp32
  const float* A   = (const float*)d_in[1];   // (64, 64) fp32
  const float* Bm  = (const float*)d_in[2];   // (64, 1) fp32
  float* out = (float*)d_out;                 // (2048, 8, 64, 64) fp32

  float* ws = (float*)d_ws;
  float* A64 = ws;                            // 4096 f32   (16 KB)
  float* Kv  = ws + 4096;                     // 4096 f32   (16 KB)
  f16*  W16  = (f16*)(ws + 8192);             // 4096*256 f16 (2 MB)
  f16*  R16  = (f16*)((char*)d_ws + 2129920); // 16384*256 f16 (8 MB)

  hipLaunchKernelGGL(kA_pow,  dim3(192),  dim3(1024), 0, stream, A, Bm, inp, A64, Kv, W16, R16);
  hipLaunchKernelGGL(kB_prep, dim3(192),  dim3(256),  0, stream, inp, Kv, A64, R16, W16);
  hipLaunchKernelGGL(kC_gemm, dim3(4096), dim3(256),  0, stream, R16, W16, out);
}